// Round 9
// baseline (498.502 us; speedup 1.0000x reference)
//
#include <hip/hip_runtime.h>
#include <hip/hip_bf16.h>

#define DIM 512
#define BB 8
#define LL 8192
#define ML (BB * LL)  // 65536 rows

typedef __attribute__((ext_vector_type(4))) float f32x4;
typedef __attribute__((ext_vector_type(8))) short short8;

__device__ __forceinline__ unsigned short bf16_bits(float f) {
  __hip_bfloat16 h = __float2bfloat16(f);
  return *reinterpret_cast<unsigned short*>(&h);
}

// ---------------- zero the row-sumsq accumulator ----------------------------
__global__ void zero_ss(float* __restrict__ ss) {
  ss[blockIdx.x * 256 + threadIdx.x] = 0.0f;
}

// ---------------- depthwise causal conv (K=4, left pad 3) + cast to bf16 ----
__global__ void conv_cast_kernel(const float* __restrict__ x,
                                 const float* __restrict__ cwt,
                                 const float* __restrict__ cb,
                                 __hip_bfloat16* __restrict__ xc) {
  const int tid = blockIdx.x * 256 + threadIdx.x;
  const int d = (tid & 127) << 2;  // 0..508 step 4
  const int bl = tid >> 7;
  const int l = bl & (LL - 1);
  float4 acc = *(const float4*)(cb + d);
  float4 w[4];
#pragma unroll
  for (int k = 0; k < 4; ++k) w[k] = *(const float4*)(cwt + k * DIM + d);
#pragma unroll
  for (int k = 0; k < 4; ++k) {
    if (l - 3 + k >= 0) {
      const float4 xv = *(const float4*)(x + (size_t)(bl - 3 + k) * DIM + d);
      acc.x += xv.x * w[k].x;
      acc.y += xv.y * w[k].y;
      acc.z += xv.z * w[k].z;
      acc.w += xv.w * w[k].w;
    }
  }
  ushort4 o;
  o.x = bf16_bits(acc.x);
  o.y = bf16_bits(acc.y);
  o.z = bf16_bits(acc.z);
  o.w = bf16_bits(acc.w);
  *(ushort4*)((unsigned short*)xc + (size_t)bl * DIM + d) = o;
}

// ---------------- weight prep: cast (or transpose-cast) one 512x512 weight --
__global__ void prep_w(const float* __restrict__ src,
                       __hip_bfloat16* __restrict__ dst, int transpose,
                       const float* __restrict__ cw, float* __restrict__ cwt) {
  const int i = blockIdx.x * 256 + threadIdx.x;  // 0..262143
  if (transpose)
    dst[(size_t)(i & 511) * DIM + (i >> 9)] = __float2bfloat16(src[i]);
  else
    dst[i] = __float2bfloat16(src[i]);
  if (cwt != nullptr && i < DIM * 4) cwt[(i & 3) * DIM + (i >> 2)] = cw[i];
}

// ---------------- GEMM: C[M,512] = A[M,512](bf16) @ Bt[512,512](bf16)^T -----
// NO LDS, NO barriers. B (512 KB) is L2-resident; A's only reuse is
// in-register -> staging was pure overhead for this shape (guide CM#7).
// Each wave independently owns a 64x64 output tile: per K-step 8 coalesced
// 16B/lane global loads (4 A-frags + 4 B-frags) -> 16 MFMA. Block = 4 waves
// stacked on M (share B-frags via L1). T1 XCD swizzle: 8 bn-tiles of one bm
// per XCD -> A once from HBM, B from L2.
// EPI 0: write C1 bf16 + per-row sum-of-squares atomics into ss
// EPI 1: v *= 1/max(sqrt(ss[r]),eps); exact GELU -> bf16
// EPI 2: out f32 = v + (1/max(sqrt(ss[r]),eps)) * C1_bf16[off]
template <int EPI>
__global__ __launch_bounds__(256, 3) void gemm_direct(
    const __hip_bfloat16* __restrict__ A, const __hip_bfloat16* __restrict__ Bt,
    float* __restrict__ Cf, __hip_bfloat16* __restrict__ Cb,
    const __hip_bfloat16* __restrict__ C1, float* __restrict__ ss) {
  // T1: XCD-chunked swizzle; grid = 2048 (%8==0)
  const int bid = blockIdx.x;
  const int swz = (bid & 7) * (gridDim.x >> 3) + (bid >> 3);
  const int bm = swz >> 3;  // nbn = 512/64 = 8
  const int bn = swz & 7;
  const int tid = threadIdx.x;
  const int wv = tid >> 6, ln = tid & 63;
  const int idx = ln & 15, kg = ln >> 4;
  const size_t rowA = (size_t)bm * 256 + wv * 64;  // wave's 64 M-rows
  const size_t rowB = (size_t)bn * 64;             // wave's 64 N-cols

  // per-lane fragment base pointers (16B contiguous per lane, coalesced)
  const __hip_bfloat16* pA = A + (rowA + idx) * DIM + kg * 8;
  const __hip_bfloat16* pB = Bt + (rowB + idx) * DIM + kg * 8;

  f32x4 acc[4][4] = {};

#pragma unroll 2
  for (int t = 0; t < 16; ++t) {
    const int k0 = t << 5;
    short8 af[4], bfv[4];
#pragma unroll
    for (int mi = 0; mi < 4; ++mi)
      af[mi] = *(const short8*)(pA + (size_t)mi * 16 * DIM + k0);
#pragma unroll
    for (int ni = 0; ni < 4; ++ni)
      bfv[ni] = *(const short8*)(pB + (size_t)ni * 16 * DIM + k0);
#pragma unroll
    for (int mi = 0; mi < 4; ++mi)
#pragma unroll
      for (int ni = 0; ni < 4; ++ni)
        acc[mi][ni] = __builtin_amdgcn_mfma_f32_16x16x32_bf16(
            af[mi], bfv[ni], acc[mi][ni], 0, 0, 0);
  }

  // epilogue: C/D layout col = lane&15, row = (lane>>4)*4 + j  [m89-verified]
  const int cr0 = (int)rowA;
  const int cc0 = (int)rowB;
#pragma unroll
  for (int mi = 0; mi < 4; ++mi) {
#pragma unroll
    for (int j = 0; j < 4; ++j) {
      const int r = cr0 + mi * 16 + kg * 4 + j;
      if (EPI == 0) {
        float ps = 0.0f;
#pragma unroll
        for (int ni = 0; ni < 4; ++ni) {
          const float v = acc[mi][ni][j];
          ps += v * v;
          Cb[(size_t)r * DIM + cc0 + ni * 16 + idx] = __float2bfloat16(v);
        }
        ps += __shfl_xor(ps, 1, 64);
        ps += __shfl_xor(ps, 2, 64);
        ps += __shfl_xor(ps, 4, 64);
        ps += __shfl_xor(ps, 8, 64);
        if (idx == 0) atomicAdd(ss + r, ps);
      } else {
        const float sc = 1.0f / fmaxf(sqrtf(ss[r]), 1e-12f);
#pragma unroll
        for (int ni = 0; ni < 4; ++ni) {
          const size_t off = (size_t)r * DIM + cc0 + ni * 16 + idx;
          if (EPI == 1) {
            const float v = acc[mi][ni][j] * sc;
            const float ge =
                0.5f * v * (1.0f + erff(v * 0.70710678118654752f));
            Cb[off] = __float2bfloat16(ge);
          } else {
            Cf[off] = acc[mi][ni][j] + sc * __bfloat162float(C1[off]);
          }
        }
      }
    }
  }
}

extern "C" void kernel_launch(void* const* d_in, const int* in_sizes, int n_in,
                              void* d_out, int out_size, void* d_ws,
                              size_t ws_size, hipStream_t stream) {
  const float* x = (const float*)d_in[0];
  const float* cw = (const float*)d_in[1];
  const float* cb = (const float*)d_in[2];
  const float* qw = (const float*)d_in[3];
  const float* w1 = (const float*)d_in[4];
  const float* w2 = (const float*)d_in[5];
  float* out = (float*)d_out;

  // ws layout (high-water 135.54 MB, under proven-safe 135.79 MB):
  //   [0, 64Mi)        x_conv bf16, reused as g (gelu out) after GEMM1
  //   [64Mi, 128Mi)    C1 bf16 (pre-normalize q-GEMM output; lives to GEMM3)
  //   [128Mi, +512K)   weight slot A (bf16)
  //   [+512K, +1M)     weight slot B (bf16)
  //   [+1M, +1M+8K)    cwt f32 [4][512]
  //   [+1M+8K, +1.25M) ss f32 [ML] row sum-of-squares
  char* ws = (char*)d_ws;
  __hip_bfloat16* xconv = (__hip_bfloat16*)ws;
  __hip_bfloat16* C1 = (__hip_bfloat16*)(ws + (size_t)67108864);
  __hip_bfloat16* wA = (__hip_bfloat16*)(ws + (size_t)134217728);
  __hip_bfloat16* wB = wA + DIM * DIM;
  float* cwt = (float*)(ws + (size_t)134217728 + 1048576);
  float* ss = (float*)(ws + (size_t)134217728 + 1048576 + 8192);
  __hip_bfloat16* g = xconv;  // alias: x_conv dead after GEMM1

  const int gemm_grid = (ML / 256) * (DIM / 64);  // 2048 (%8==0 for T1)

  zero_ss<<<ML / 256, 256, 0, stream>>>(ss);
  prep_w<<<DIM * DIM / 256, 256, 0, stream>>>(qw, wA, 0, cw, cwt);
  prep_w<<<DIM * DIM / 256, 256, 0, stream>>>(w1, wB, 1, nullptr, nullptr);
  conv_cast_kernel<<<ML * (DIM / 4) / 256, 256, 0, stream>>>(x, cwt, cb, xconv);
  // GEMM1: C1 = x_conv @ q_w^T (bf16) + row sumsq -> ss
  gemm_direct<0><<<gemm_grid, 256, 0, stream>>>(xconv, wA, nullptr, C1,
                                                nullptr, ss);
  prep_w<<<DIM * DIM / 256, 256, 0, stream>>>(w2, wA, 1, nullptr, nullptr);
  // GEMM2: g = gelu(sc * (C1 @ w1)) -> bf16 (into x_conv's region)
  gemm_direct<1><<<gemm_grid, 256, 0, stream>>>(C1, wB, nullptr, g, nullptr,
                                                ss);
  // GEMM3: out = sc*C1 + g @ w2 -> f32
  gemm_direct<2><<<gemm_grid, 256, 0, stream>>>(g, wA, out, nullptr, C1, ss);
}

// Round 10
// 258.049 us; speedup vs baseline: 1.9318x; 1.9318x over previous
//
#include <hip/hip_runtime.h>
#include <hip/hip_bf16.h>

#define DIM 512
#define BB 8
#define LL 8192
#define ML (BB * LL)  // 65536 rows

typedef __attribute__((ext_vector_type(4))) float f32x4;
typedef __attribute__((ext_vector_type(8))) short short8;

__device__ __forceinline__ void gl_lds16(const __hip_bfloat16* g, __hip_bfloat16* l) {
  __builtin_amdgcn_global_load_lds(
      (const __attribute__((address_space(1))) void*)g,
      (__attribute__((address_space(3))) void*)l, 16, 0, 0);
}

// inline-asm LDS read; ordering owned by us (rule #18)
__device__ __forceinline__ short8 ds_read128(const __hip_bfloat16* p) {
  short8 r;
  asm volatile("ds_read_b128 %0, %1"
               : "=v"(r)
               : "v"((const __attribute__((address_space(3))) void*)p));
  return r;
}

__device__ __forceinline__ unsigned short bf16_bits(float f) {
  __hip_bfloat16 h = __float2bfloat16(f);
  return *reinterpret_cast<unsigned short*>(&h);
}

// Packed tile-major layout for all GEMM operands: element (r, k) of a
// [rows][512] bf16 matrix lives in tile (r>>7, k>>5) = 8KB block
// (r&127 rows x 32 k), internal [row][chunk-pos][8], with the T2 XOR
// (chunk-pos = chunk ^ ((r>>1)&3)) PRE-BAKED. gl_lds staging of a tile is
// then a fully SEQUENTIAL 8KB burst (16-contiguous-line requests) instead
// of 16B-every-1KB fragments -> MSHR/line-request friendly.
__device__ __forceinline__ size_t packA(int r, int k) {
  return ((size_t)((r >> 7) * 16 + (k >> 5))) * 4096 + (r & 127) * 32 +
         (((((k >> 3) & 3) ^ ((r >> 1) & 3))) << 3) + (k & 7);
}

// ---------------- zero the row-sumsq accumulator ----------------------------
__global__ void zero_ss(float* __restrict__ ss) {
  ss[blockIdx.x * 256 + threadIdx.x] = 0.0f;
}

// ---------------- depthwise causal conv (K=4, left pad 3) -> packed bf16 ----
__global__ void conv_cast_kernel(const float* __restrict__ x,
                                 const float* __restrict__ cwt,
                                 const float* __restrict__ cb,
                                 __hip_bfloat16* __restrict__ xc) {
  const int tid = blockIdx.x * 256 + threadIdx.x;
  const int d = (tid & 127) << 2;  // 0..508 step 4
  const int bl = tid >> 7;
  const int l = bl & (LL - 1);
  float4 acc = *(const float4*)(cb + d);
  float4 w[4];
#pragma unroll
  for (int k = 0; k < 4; ++k) w[k] = *(const float4*)(cwt + k * DIM + d);
#pragma unroll
  for (int k = 0; k < 4; ++k) {
    if (l - 3 + k >= 0) {
      const float4 xv = *(const float4*)(x + (size_t)(bl - 3 + k) * DIM + d);
      acc.x += xv.x * w[k].x;
      acc.y += xv.y * w[k].y;
      acc.z += xv.z * w[k].z;
      acc.w += xv.w * w[k].w;
    }
  }
  ushort4 o;
  o.x = bf16_bits(acc.x);
  o.y = bf16_bits(acc.y);
  o.z = bf16_bits(acc.z);
  o.w = bf16_bits(acc.w);
  // packed write: d..d+3 stays within one 8-elem chunk half -> contiguous 8B
  *(ushort4*)((unsigned short*)xc + packA(bl, d)) = o;
}

// ---------------- weight prep: cast (or transpose-cast) into packed layout --
__global__ void prep_w(const float* __restrict__ src,
                       __hip_bfloat16* __restrict__ dst, int transpose,
                       const float* __restrict__ cw, float* __restrict__ cwt) {
  const int i = blockIdx.x * 256 + threadIdx.x;  // 0..262143
  if (transpose) {
    const int k = i >> 9, n = i & 511;  // src[k][n] -> Bt[n][k]
    dst[packA(n, k)] = __float2bfloat16(src[i]);
  } else {
    const int n = i >> 9, k = i & 511;  // src already [n][k]
    dst[packA(n, k)] = __float2bfloat16(src[i]);
  }
  if (cwt != nullptr && i < DIM * 4) cwt[(i & 3) * DIM + (i >> 2)] = cw[i];
}

// ---------------- GEMM: C[M,512] = A[M,512](bf16,packed) @ Bt(packed)^T -----
// R7 structure verbatim (128x128, BK=32, 4 waves, ring-3 depth-2, counted
// vmcnt, asm ds_read) -- ONLY the staging source changed to packed tiles:
// each STAGE is a sequential 8KB burst per operand.
// EPI 0: write C1 PACKED bf16 + per-row sumsq atomics into ss
// EPI 1: v *= 1/max(sqrt(ss[r]),eps); exact GELU -> PACKED bf16
// EPI 2: out(row-major f32) = v + sc * C1_packed[r,c]
template <int EPI>
__global__ __launch_bounds__(256) void gemm_bt(
    const __hip_bfloat16* __restrict__ A, const __hip_bfloat16* __restrict__ Bt,
    float* __restrict__ Cf, __hip_bfloat16* __restrict__ Cb,
    const __hip_bfloat16* __restrict__ C1, float* __restrict__ ss) {
  __shared__ __hip_bfloat16 sA[3][128 * 32];
  __shared__ __hip_bfloat16 sB[3][128 * 32];
  // T1: XCD-chunked swizzle (gridDim = 2048, %8 == 0)
  const int bid = blockIdx.x;
  const int swz = (bid & 7) * (gridDim.x >> 3) + (bid >> 3);
  const int bm = swz >> 2;  // nbn = 512/128 = 4
  const int bn = swz & 3;
  const int tid = threadIdx.x;
  const int wv = tid >> 6, ln = tid & 63;
  const int wr = wv >> 1, wc = wv & 1;
  const int idx = ln & 15, kg = ln >> 4;

  f32x4 acc[4][4] = {};

  // read-side T2 (baked into packed layout): chunk kg at row lives at
  // position kg ^ ((idx>>1)&3)
  const int kgx = ((kg ^ ((idx >> 1) & 3)) << 3);  // elements

  // packed panels: A tile-row bm = 16 sequential 8KB tiles; B likewise
  const __hip_bfloat16* gA = A + (size_t)bm * 16 * 4096;
  const __hip_bfloat16* gB = Bt + (size_t)bn * 16 * 4096;
  const int e0 = wv * 512;         // wave's instr-0 element offset in tile
  const int e1 = 2048 + wv * 512;  // wave's instr-1 element offset
  const __hip_bfloat16* gAl = gA + e0 + ln * 8;  // per-lane (contiguous 16B)
  const __hip_bfloat16* gBl = gB + e0 + ln * 8;

  const int nt = 16;  // 512/32 K-steps

#define STAGE(t, b)                                  \
  do {                                               \
    const int o_ = (t) * 4096;                       \
    gl_lds16(gAl + o_, &sA[(b)][e0]);                \
    gl_lds16(gAl + o_ + 2048, &sA[(b)][e1]);         \
    gl_lds16(gBl + o_, &sB[(b)][e0]);                \
    gl_lds16(gBl + o_ + 2048, &sB[(b)][e1]);         \
  } while (0)

  // prologue: fill ring slots 0,1 (8 vm instructions outstanding)
  STAGE(0, 0);
  STAGE(1, 1);

  int rb = 0;  // read buffer; write slot = (rb+2)%3
  for (int t = 0; t < nt; ++t) {
    if (t + 1 < nt)
      asm volatile("s_waitcnt vmcnt(4)" ::: "memory");
    else
      asm volatile("s_waitcnt vmcnt(0)" ::: "memory");
    asm volatile("s_barrier" ::: "memory");
    if (t + 2 < nt) {
      const int wbuf = rb < 1 ? rb + 2 : rb - 1;  // (rb+2)%3
      STAGE(t + 2, wbuf);
    }
    short8 af[4], bfv[4];
#pragma unroll
    for (int mi = 0; mi < 4; ++mi)
      af[mi] = ds_read128(&sA[rb][(wr * 64 + mi * 16 + idx) * 32 + kgx]);
#pragma unroll
    for (int ni = 0; ni < 4; ++ni)
      bfv[ni] = ds_read128(&sB[rb][(wc * 64 + ni * 16 + idx) * 32 + kgx]);
    asm volatile("s_waitcnt lgkmcnt(0)" ::: "memory");
    __builtin_amdgcn_sched_barrier(0);  // rule #18
    __builtin_amdgcn_s_setprio(1);
#pragma unroll
    for (int mi = 0; mi < 4; ++mi)
#pragma unroll
      for (int ni = 0; ni < 4; ++ni)
        acc[mi][ni] = __builtin_amdgcn_mfma_f32_16x16x32_bf16(
            af[mi], bfv[ni], acc[mi][ni], 0, 0, 0);
    __builtin_amdgcn_s_setprio(0);
    rb = rb == 2 ? 0 : rb + 1;
  }
#undef STAGE

  // epilogue: C/D layout col = lane&15, row = (lane>>4)*4 + j  [m89-verified]
  const int cr0 = bm * 128 + wr * 64;
  const int cc0 = bn * 128 + wc * 64;
#pragma unroll
  for (int mi = 0; mi < 4; ++mi) {
#pragma unroll
    for (int j = 0; j < 4; ++j) {
      const int r = cr0 + mi * 16 + kg * 4 + j;
      if (EPI == 0) {
        float ps = 0.0f;
#pragma unroll
        for (int ni = 0; ni < 4; ++ni) {
          const float v = acc[mi][ni][j];
          ps += v * v;
          Cb[packA(r, cc0 + ni * 16 + idx)] = __float2bfloat16(v);
        }
        ps += __shfl_xor(ps, 1, 64);
        ps += __shfl_xor(ps, 2, 64);
        ps += __shfl_xor(ps, 4, 64);
        ps += __shfl_xor(ps, 8, 64);
        if (idx == 0) atomicAdd(ss + r, ps);
      } else {
        const float sc = 1.0f / fmaxf(sqrtf(ss[r]), 1e-12f);
#pragma unroll
        for (int ni = 0; ni < 4; ++ni) {
          const int c = cc0 + ni * 16 + idx;
          if (EPI == 1) {
            const float v = acc[mi][ni][j] * sc;
            const float ge =
                0.5f * v * (1.0f + erff(v * 0.70710678118654752f));
            Cb[packA(r, c)] = __float2bfloat16(ge);
          } else {
            Cf[(size_t)r * DIM + c] =
                acc[mi][ni][j] + sc * __bfloat162float(C1[packA(r, c)]);
          }
        }
      }
    }
  }
}

extern "C" void kernel_launch(void* const* d_in, const int* in_sizes, int n_in,
                              void* d_out, int out_size, void* d_ws,
                              size_t ws_size, hipStream_t stream) {
  const float* x = (const float*)d_in[0];
  const float* cw = (const float*)d_in[1];
  const float* cb = (const float*)d_in[2];
  const float* qw = (const float*)d_in[3];
  const float* w1 = (const float*)d_in[4];
  const float* w2 = (const float*)d_in[5];
  float* out = (float*)d_out;

  // ws layout (high-water 135.54 MB, under proven-safe 135.79 MB):
  //   [0, 64Mi)        x_conv packed bf16, reused as g after GEMM1
  //   [64Mi, 128Mi)    C1 packed bf16 (lives to GEMM3)
  //   [128Mi, +512K)   weight slot A (packed bf16)
  //   [+512K, +1M)     weight slot B (packed bf16)
  //   [+1M, +1M+8K)    cwt f32 [4][512]
  //   [+1M+8K, +1.25M) ss f32 [ML]
  char* ws = (char*)d_ws;
  __hip_bfloat16* xconv = (__hip_bfloat16*)ws;
  __hip_bfloat16* C1 = (__hip_bfloat16*)(ws + (size_t)67108864);
  __hip_bfloat16* wA = (__hip_bfloat16*)(ws + (size_t)134217728);
  __hip_bfloat16* wB = wA + DIM * DIM;
  float* cwt = (float*)(ws + (size_t)134217728 + 1048576);
  float* ss = (float*)(ws + (size_t)134217728 + 1048576 + 8192);
  __hip_bfloat16* g = xconv;  // alias: x_conv dead after GEMM1

  const int gemm_grid = (ML / 128) * (DIM / 128);  // 2048 (%8==0 for T1)

  zero_ss<<<ML / 256, 256, 0, stream>>>(ss);
  prep_w<<<DIM * DIM / 256, 256, 0, stream>>>(qw, wA, 0, cw, cwt);
  prep_w<<<DIM * DIM / 256, 256, 0, stream>>>(w1, wB, 1, nullptr, nullptr);
  conv_cast_kernel<<<ML * (DIM / 4) / 256, 256, 0, stream>>>(x, cwt, cb, xconv);
  // GEMM1: C1 = x_conv @ q_w^T (packed bf16) + row sumsq -> ss
  gemm_bt<0><<<gemm_grid, 256, 0, stream>>>(xconv, wA, nullptr, C1, nullptr,
                                            ss);
  prep_w<<<DIM * DIM / 256, 256, 0, stream>>>(w2, wA, 1, nullptr, nullptr);
  // GEMM2: g = gelu(sc * (C1 @ w1)) -> packed bf16 (into x_conv's region)
  gemm_bt<1><<<gemm_grid, 256, 0, stream>>>(C1, wB, nullptr, g, nullptr, ss);
  // GEMM3: out = sc*C1 + g @ w2 -> f32 row-major
  gemm_bt<2><<<gemm_grid, 256, 0, stream>>>(g, wA, out, nullptr, C1, ss);
}